// Round 8
// baseline (30.384 us; speedup 1.0000x reference)
//
#include <hip/hip_runtime.h>

#define HH 48
#define WW 48
#define HW 2304   // 48*48
#define NB 8      // N
#define CB 4      // COLOR
#define TB 3      // RGB

// pred_img_i[b,n,t,y,x] = 0.25 * sum_c sum_s kw[b,n,s,t,y,x] *
//     sum_{i,j in KxK} c1[b,n,cur_s+i,c,t,y,x]*c2[b,n,cur_s+j,c,t,y,x]
//                      * F[b,n,c, y+i+p_s-3, x+j+p_s-3]
// s=0:K=7,cur=9  s=1:K=5,cur=4  s=2:K=3,cur=1  s=3:K=1,cur=0
//
// Fused: block = 256 threads = 4 waves; wave c handles color c of the same
// 64-pixel chunk of one (b,n,t). Phased per-thread body (R6) to keep VGPR low.
// LDS c-reduce; lanes 0..63 write pred_img_i AND atomicAdd the n-mean into
// pred_img (pm zeroed via hipMemsetAsync each call). Single dependent kernel.
__global__ __launch_bounds__(256) void kconv_fused(
    const float* __restrict__ frames,   // (4, 8, 4, 48, 48)
    const float* __restrict__ core,     // (4, 3072, 48, 48)  ch=((n*32+q)*4+c)*3+t
    const float* __restrict__ kw,       // (4, 8, 4, 3, 48, 48)
    float* __restrict__ out,            // pred_img_i (4, 8, 3, 48, 48)
    float* __restrict__ pm)             // pred_img   (4, 3, 48, 48), pre-zeroed
{
    const int blk = blockIdx.x;          // 4*8*3*36 = 3456
    const int pc  = blk % (HW / 64);     // 64-pixel chunk, 36 per image
    int rem = blk / (HW / 64);
    const int t = rem % TB; rem /= TB;
    const int n = rem % NB;
    const int b = rem / NB;
    const int tix = threadIdx.x;         // 0..255
    const int c   = tix >> 6;            // wave id = color
    const int p64 = tix & 63;
    const int pix = pc * 64 + p64;
    const int x = pix % WW;
    const int y = pix / WW;

    const float* cp = core + ((size_t)b * 3072 + (size_t)((n * 32) * CB + c) * 3 + t) * HW + pix;

    // phase 1: column weights bv[16]
    float bv[16];
    #pragma unroll
    for (int q = 0; q < 16; ++q)
        bv[q] = cp[(size_t)((q + 16) * 12) * HW];

    // x clamps/masks hoisted out of the row loop
    int   xoff[7];
    float xmsk[7];
    #pragma unroll
    for (int j = 0; j < 7; ++j) {
        const int xx = x + j - 3;
        xoff[j] = min(max(xx, 0), WW - 1);
        xmsk[j] = ((xx >= 0) & (xx < WW)) ? 1.f : 0.f;
    }

    const float* fb = frames + ((size_t)(b * NB + n) * CB + c) * HW;

    // phase 2: per-row inner sums (fp[] transient)
    float in7[7], in5[5], in3[3], f1 = 0.f;
    #pragma unroll
    for (int i = 0; i < 7; ++i) {
        const int yy = y + i - 3;
        const float ymsk = ((yy >= 0) & (yy < HH)) ? 1.f : 0.f;
        const float* frow = fb + min(max(yy, 0), HH - 1) * WW;
        float fp[7];
        #pragma unroll
        for (int j = 0; j < 7; ++j)
            fp[j] = frow[xoff[j]] * (ymsk * xmsk[j]);   // branchless zero-pad
        float s7 = 0.f;
        #pragma unroll
        for (int j = 0; j < 7; ++j) s7 = fmaf(bv[9 + j], fp[j], s7);
        in7[i] = s7;
        if (i >= 1 && i <= 5) {
            float s5 = 0.f;
            #pragma unroll
            for (int j = 0; j < 5; ++j) s5 = fmaf(bv[4 + j], fp[1 + j], s5);
            in5[i - 1] = s5;
        }
        if (i >= 2 && i <= 4) {
            float s3 = 0.f;
            #pragma unroll
            for (int j = 0; j < 3; ++j) s3 = fmaf(bv[1 + j], fp[2 + j], s3);
            in3[i - 2] = s3;
        }
        if (i == 3) f1 = bv[0] * fp[3];
    }

    // keep a[]/kw loads from being hoisted above (peak-pressure control)
    __builtin_amdgcn_sched_barrier(0);

    // phase 3: row weights + kernel_weight, final dots
    float a[16];
    #pragma unroll
    for (int q = 0; q < 16; ++q)
        a[q] = cp[(size_t)(q * 12) * HW];

    const float* kwp = kw + ((size_t)(b * NB + n) * 12 + t) * HW + pix;
    const float kw0 = kwp[0];
    const float kw1 = kwp[(size_t)3 * HW];
    const float kw2 = kwp[(size_t)6 * HW];
    const float kw3 = kwp[(size_t)9 * HW];

    float r7 = 0.f, r5 = 0.f, r3 = 0.f;
    #pragma unroll
    for (int i = 0; i < 7; ++i) r7 = fmaf(a[9 + i], in7[i], r7);
    #pragma unroll
    for (int i = 0; i < 5; ++i) r5 = fmaf(a[4 + i], in5[i], r5);
    #pragma unroll
    for (int i = 0; i < 3; ++i) r3 = fmaf(a[1 + i], in3[i], r3);
    const float r1 = a[0] * f1;

    const float val = fmaf(kw0, r7, fmaf(kw1, r5, fmaf(kw2, r3, kw3 * r1)));

    // LDS reduce over c (1 KB; 2 lanes/bank = free)
    __shared__ float lds[CB][64];
    lds[c][p64] = val;
    __syncthreads();
    if (tix < 64) {
        const float s4 = 0.25f * (lds[0][tix] + lds[1][tix] + lds[2][tix] + lds[3][tix]);
        out[((size_t)(b * NB + n) * TB + t) * HW + pc * 64 + tix] = s4;
        // n-mean: 8 blocks (one per n) accumulate into pred_img
        atomicAdd(&pm[((size_t)b * TB + t) * HW + pc * 64 + tix], 0.125f * s4);
    }
}

extern "C" void kernel_launch(void* const* d_in, const int* in_sizes, int n_in,
                              void* d_out, int out_size, void* d_ws, size_t ws_size,
                              hipStream_t stream) {
    const float* frames = (const float*)d_in[0];
    const float* core   = (const float*)d_in[1];
    const float* kw     = (const float*)d_in[2];
    float* out = (float*)d_out;                 // pred_img_i: 221184 floats
    float* pm  = out + (size_t)4 * NB * TB * HW; // pred_img:   27648 floats

    hipMemsetAsync(pm, 0, (size_t)4 * TB * HW * sizeof(float), stream);
    kconv_fused<<<4 * NB * TB * (HW / 64), 256, 0, stream>>>(frames, core, kw, out, pm);
}